// Round 15
// baseline (76.100 us; speedup 1.0000x reference)
//
#include <hip/hip_runtime.h>

typedef __attribute__((ext_vector_type(2))) _Float16 h2;
typedef __attribute__((ext_vector_type(2))) __fp16 p2;   // cvt_pkrtz return type
typedef __attribute__((ext_vector_type(8))) _Float16 f16x8;
typedef __attribute__((ext_vector_type(4))) float fv4;
typedef __attribute__((ext_vector_type(4))) int iv4;
typedef __attribute__((ext_vector_type(2))) int iv2;
typedef unsigned int u32;

#define K_IN 4096
#define N_OUT 4096
#define NG 520    /* granules (8 f16) per extended row: 512 main + 8 ext */

// Fragment-major: f16 element (row,k) lives at
//   [(((row>>4)*NG + (k>>3))*16 + (row&15))*8 + (k&7)]

// ---------------------------------------------------------------------------
// ONE prep launch, grid split (2304 blocks) -- unchanged from R14 (proven):
//   bid <  1024        : xa dots row b=bid -> xp ext granules 512..519
//   1024 <= bid < 2048 : W dequant (cb = idx>>2, chunk-pair = idx&3)
//   2048 <= bid < 2304 : xp main granules (rb, k-quarter)  (LDS transpose)
// ---------------------------------------------------------------------------
__global__ __launch_bounds__(256) void prep_one(
        const float* __restrict__ x, const float* __restrict__ la,
        const int* __restrict__ qw, const float* __restrict__ sc,
        const float* __restrict__ lb, const float* __restrict__ alphap,
        _Float16* __restrict__ Wp, _Float16* __restrict__ xp)
{
    __shared__ __align__(16) char lsm[16640];
    int bid = blockIdx.x;
    int t = threadIdx.x;

    if (bid < 1024) {
        float (*red)[16] = (float (*)[16])(lsm + 16384);
        int b = bid, rb = b >> 4, rl = b & 15;
        const fv4* xp4 = (const fv4*)(x + (size_t)b * K_IN);
        fv4 xv[4];
#pragma unroll
        for (int j = 0; j < 4; ++j) xv[j] = xp4[t + j * 256];
        float acc[16];
#pragma unroll
        for (int r = 0; r < 16; ++r) {
            const fv4* ap = (const fv4*)(la + (size_t)r * K_IN);
            float s = 0.f;
#pragma unroll
            for (int j = 0; j < 4; ++j) {
                fv4 av = ap[t + j * 256];
                s = fmaf(xv[j].x, av.x, s);
                s = fmaf(xv[j].y, av.y, s);
                s = fmaf(xv[j].z, av.z, s);
                s = fmaf(xv[j].w, av.w, s);
            }
            acc[r] = s;
        }
#pragma unroll
        for (int r = 0; r < 16; ++r) {
#pragma unroll
            for (int off = 1; off < 64; off <<= 1)
                acc[r] += __shfl_xor(acc[r], off);
        }
        int lane = t & 63, w = t >> 6;
        if (lane < 16) red[w][lane] = acc[lane];
        __syncthreads();
        if (t < 8) {
            int gl = t;
            union { p2 h[4]; iv4 v; } u;
            u.v = iv4{0, 0, 0, 0};
            if (gl < 2) {
#pragma unroll
                for (int e2 = 0; e2 < 4; ++e2) {
                    int k0 = gl * 8 + e2 * 2;
                    float v0 = red[0][k0] + red[1][k0] + red[2][k0] + red[3][k0];
                    float v1 = red[0][k0+1] + red[1][k0+1] + red[2][k0+1] + red[3][k0+1];
                    u.h[e2] = __builtin_amdgcn_cvt_pkrtz(v0, v1);
                }
            }
            *(iv4*)(xp + (((size_t)rb * NG + 512 + gl) * 16 + rl) * 8) = u.v;
        }
    } else if (bid < 2048) {
        int idx = bid - 1024;
        int cb = idx >> 2, part = idx & 3;
        int c0 = part * 2;
        int o_l = t >> 4, gi_l = t & 15;
#pragma unroll 1
        for (int chunk = c0; chunk < c0 + 2; ++chunk) {
#pragma unroll
            for (int i = 0; i < 2; ++i) {
                int gi = chunk * 32 + i * 16 + gi_l;
                int o = cb * 16 + o_l;
                const int* qp = qw + ((size_t)o * 256 + gi) * 8;
                iv4 q0 = *(const iv4*)qp;
                iv4 q1 = *(const iv4*)(qp + 4);
                float s = sc[(size_t)o * 256 + gi];
                _Float16 c0h = (_Float16)(s * (2.0f / 15.0f));
                _Float16 c1h = (_Float16)(-s);
                h2 c0v = {c0h, c0h}, c1v = {c1h, c1h};
                h2 m1024 = {(_Float16)-1024.f, (_Float16)-1024.f};
                union { h2 h[4]; iv4 v; } w0, w1;
                int vals[8] = {q0.x, q0.y, q0.z, q0.w, q1.x, q1.y, q1.z, q1.w};
#pragma unroll
                for (int e = 0; e < 8; ++e) {
                    unsigned wv = (unsigned)vals[e];
                    unsigned qb = (wv & 15u) | ((wv & 0xF0u) << 12) | 0x64006400u;
                    h2 qh;
                    __builtin_memcpy(&qh, &qb, 4);
                    h2 r = (qh + m1024) * c0v + c1v;
                    if (e < 4) w0.h[e] = r; else w1.h[e - 4] = r;
                }
                int gl0 = i * 32 + 2 * gi_l;
                int s0 = o_l ^ gi_l;
                *(iv4*)(lsm + (gl0 * 16 + s0) * 16) = w0.v;
                *(iv4*)(lsm + ((gl0 + 1) * 16 + s0) * 16) = w1.v;
            }
            __syncthreads();
#pragma unroll
            for (int i = 0; i < 4; ++i) {
                int s_ = t + i * 256;
                int gl = s_ >> 4, oo = s_ & 15;
                iv4 v = *(const iv4*)(lsm + (gl * 16 + (oo ^ ((gl >> 1) & 15))) * 16);
                *(iv4*)(Wp + (((size_t)cb * NG + chunk * 64) * 16 + s_) * 8) = v;
            }
            __syncthreads();
        }
        if (part == 0 && t < 128) {
            int gl = t >> 4, rl = t & 15;
            int o = cb * 16 + rl;
            union { p2 h[4]; iv4 v; } u;
            u.v = iv4{0, 0, 0, 0};
            if (gl < 2) {
                float al = alphap[0];
                const float* wp = lb + (size_t)o * 16 + gl * 8;
#pragma unroll
                for (int e = 0; e < 4; ++e)
                    u.h[e] = __builtin_amdgcn_cvt_pkrtz(al * wp[2 * e], al * wp[2 * e + 1]);
            }
            *(iv4*)(Wp + (((size_t)cb * NG + 512 + gl) * 16 + rl) * 8) = u.v;
        }
    } else {
        int q2 = bid - 2048;
        int rb = q2 >> 2, kq = q2 & 3;
        int row = t >> 4, q = t & 15;
#pragma unroll 1
        for (int chunk = 0; chunk < 2; ++chunk) {
            int base_k = kq * 1024 + chunk * 512;
#pragma unroll
            for (int i = 0; i < 8; ++i) {
                int quad = q + i * 16;
                const float* p = x + (size_t)(rb * 16 + row) * K_IN + base_k + quad * 4;
                fv4 v = *(const fv4*)p;
                union { p2 h[2]; iv2 vv; } u;
                u.h[0] = __builtin_amdgcn_cvt_pkrtz(v.x, v.y);
                u.h[1] = __builtin_amdgcn_cvt_pkrtz(v.z, v.w);
                int gl = quad >> 1, sub = quad & 1;
                *(iv2*)(lsm + (gl * 16 + (row ^ (gl & 15))) * 16 + sub * 8) = u.vv;
            }
            __syncthreads();
#pragma unroll
            for (int i = 0; i < 4; ++i) {
                int s_ = t + i * 256;
                int gl = s_ >> 4, rr = s_ & 15;
                iv4 v = *(const iv4*)(lsm + (gl * 16 + (rr ^ (gl & 15))) * 16);
                *(iv4*)(xp + (((size_t)rb * NG + kq * 128 + chunk * 64) * 16 + s_) * 8) = v;
            }
            __syncthreads();
        }
    }
}

// ---------------------------------------------------------------------------
// GEMM (R11 structure, schedule-pinned): out = X @ W^T, f32 accum.
// 256 blocks x 512 thr (8 waves: wm,wn,kg=2x2x2; wave 64x64 over its k32
// half; 65 BK=64 steps). No LDS/barriers in main loop; per wave per step:
// 8 x 16B lane-loads (wave = 2 x 1KB contiguous) + 16 MFMA. Dist-1 register
// double-buffer; sched_group_barrier template [2 MFMA, 1 VMEM]x8 per half-
// iteration pins prefetch interleave (R13/R14 lesson: unpinned => VGPR~80-112
// => collapsed pipeline). LDS (64KB) only for the kg-split epilogue.
// ---------------------------------------------------------------------------
__global__ __launch_bounds__(512, 1) void qlora_gemm2(
        const _Float16* __restrict__ xp, const _Float16* __restrict__ Wp,
        float* __restrict__ out)
{
    __shared__ __align__(16) char lds[65536];

    int bid = blockIdx.x;
    int xcd = bid & 7, j = bid >> 3;    // j 0..31
    int by = j & 7, bx = xcd * 4 + (j >> 3);
    int bm0 = by << 7, bn0 = bx << 7;

    int t = threadIdx.x;
    int lane = t & 63;
    int wid = t >> 6;                   // 0..7
    int kg = wid & 1, wn = (wid >> 1) & 1, wm = wid >> 2;
    int rl = lane & 15, hq = lane >> 4;

    const char* abase[4];
    const char* bbase[4];
#pragma unroll
    for (int m = 0; m < 4; ++m) {
        int rb = by * 8 + wm * 4 + m;
        abase[m] = (const char*)xp + (((size_t)rb * NG + kg * 4 + hq) * 16 + rl) * 16;
    }
#pragma unroll
    for (int n = 0; n < 4; ++n) {
        int cb = bx * 8 + wn * 4 + n;
        bbase[n] = (const char*)Wp + (((size_t)cb * NG + kg * 4 + hq) * 16 + rl) * 16;
    }

    struct Frag { iv4 a[4]; iv4 b[4]; };
    Frag fA, fB;

    auto LOADF = [&](Frag& f, int ts) {
        size_t off = (size_t)ts * 2048;   // 8 granules * 256B
#pragma unroll
        for (int m = 0; m < 4; ++m) f.a[m] = *(const iv4*)(abase[m] + off);
#pragma unroll
        for (int n = 0; n < 4; ++n) f.b[n] = *(const iv4*)(bbase[n] + off);
    };

    fv4 acc[4][4];
#pragma unroll
    for (int m = 0; m < 4; ++m)
#pragma unroll
        for (int n = 0; n < 4; ++n)
            acc[m][n] = fv4{0.f, 0.f, 0.f, 0.f};

    auto MFMAF = [&](const Frag& f) {
        union { iv4 v; f16x8 h; } ua[4], ub[4];
#pragma unroll
        for (int m = 0; m < 4; ++m) ua[m].v = f.a[m];
#pragma unroll
        for (int n = 0; n < 4; ++n) ub[n].v = f.b[n];
        __builtin_amdgcn_s_setprio(1);
#pragma unroll
        for (int m = 0; m < 4; ++m)
#pragma unroll
            for (int n = 0; n < 4; ++n)
                acc[m][n] = __builtin_amdgcn_mfma_f32_16x16x32_f16(
                    ua[m].h, ub[n].h, acc[m][n], 0, 0, 0);
        __builtin_amdgcn_s_setprio(0);
    };

    // schedule template: 16 MFMA interleaved 2:1 with the 8 prefetch loads
    auto PIN = [&]() {
#pragma unroll
        for (int i = 0; i < 8; ++i) {
            __builtin_amdgcn_sched_group_barrier(0x008, 2, 0);  // 2 MFMA
            __builtin_amdgcn_sched_group_barrier(0x020, 1, 0);  // 1 VMEM read
        }
    };

    // ---- main loop: 65 steps, register double-buffer, no barriers ----
    LOADF(fA, 0);
#pragma unroll 1
    for (int ts = 0; ts < 64; ts += 2) {
        LOADF(fB, ts + 1);
        MFMAF(fA);
        PIN();
        LOADF(fA, ts + 2);
        MFMAF(fB);
        PIN();
    }
    MFMAF(fA);                           // ts = 64 (lora/ext step)

    // ---- kg-split reduction + store ----
    __syncthreads();
    if (kg == 1) {
        char* dmp = lds + (wm * 2 + wn) * 16384;
#pragma unroll
        for (int m = 0; m < 4; ++m)
#pragma unroll
            for (int n = 0; n < 4; ++n)
                *(fv4*)(dmp + (m * 4 + n) * 1024 + lane * 16) = acc[m][n];
    }
    __syncthreads();
    if (kg == 0) {
        const char* dmp = lds + (wm * 2 + wn) * 16384;
#pragma unroll
        for (int m = 0; m < 4; ++m) {
            int row0 = bm0 + wm * 64 + m * 16 + hq * 4;
#pragma unroll
            for (int n = 0; n < 4; ++n) {
                fv4 p = *(const fv4*)(dmp + (m * 4 + n) * 1024 + lane * 16);
                fv4 v = acc[m][n];
                v.x += p.x; v.y += p.y; v.z += p.z; v.w += p.w;
                int col = bn0 + wn * 64 + n * 16 + rl;
#pragma unroll
                for (int r = 0; r < 4; ++r)
                    out[(size_t)(row0 + r) * N_OUT + col] = v[r];
            }
        }
    }
}

extern "C" void kernel_launch(void* const* d_in, const int* in_sizes, int n_in,
                              void* d_out, int out_size, void* d_ws, size_t ws_size,
                              hipStream_t stream) {
    const float* x  = (const float*)d_in[0];
    const int*   qw = (const int*)d_in[1];
    const float* sc = (const float*)d_in[2];
    const float* la = (const float*)d_in[3];
    const float* lb = (const float*)d_in[4];
    const float* al = (const float*)d_in[5];
    float* out = (float*)d_out;

    const size_t WP_BYTES = (size_t)256 * NG * 16 * 16;   // 34,078,720
    _Float16* Wp = (_Float16*)d_ws;
    _Float16* xp = (_Float16*)((char*)d_ws + WP_BYTES);
    (void)ws_size; (void)n_in; (void)in_sizes; (void)out_size;

    prep_one<<<2304, 256, 0, stream>>>(x, la, qw, sc, lb, al, Wp, xp);
    qlora_gemm2<<<256, 512, 0, stream>>>(xp, Wp, out);
}

// Round 16
// 76.081 us; speedup vs baseline: 1.0003x; 1.0003x over previous
//
#include <hip/hip_runtime.h>

typedef __attribute__((ext_vector_type(2))) _Float16 h2;
typedef __attribute__((ext_vector_type(2))) __fp16 p2;   // cvt_pkrtz return type
typedef __attribute__((ext_vector_type(8))) _Float16 f16x8;
typedef __attribute__((ext_vector_type(4))) float fv4;
typedef __attribute__((ext_vector_type(4))) int iv4;
typedef __attribute__((ext_vector_type(2))) int iv2;
typedef unsigned int u32;

#define K_IN 4096
#define N_OUT 4096
#define NG 520    /* granules (8 f16) per extended row: 512 main + 8 ext */

// Fragment-major: f16 element (row,k) lives at
//   [(((row>>4)*NG + (k>>3))*16 + (row&15))*8 + (k&7)]

// ---------------------------------------------------------------------------
// ONE prep launch, grid split (2304 blocks) -- unchanged (proven):
//   bid <  1024        : xa dots row b=bid -> xp ext granules 512..519
//   1024 <= bid < 2048 : W dequant (cb = idx>>2, chunk-pair = idx&3)
//   2048 <= bid < 2304 : xp main granules (rb, k-quarter)  (LDS transpose)
// ---------------------------------------------------------------------------
__global__ __launch_bounds__(256) void prep_one(
        const float* __restrict__ x, const float* __restrict__ la,
        const int* __restrict__ qw, const float* __restrict__ sc,
        const float* __restrict__ lb, const float* __restrict__ alphap,
        _Float16* __restrict__ Wp, _Float16* __restrict__ xp)
{
    __shared__ __align__(16) char lsm[16640];
    int bid = blockIdx.x;
    int t = threadIdx.x;

    if (bid < 1024) {
        float (*red)[16] = (float (*)[16])(lsm + 16384);
        int b = bid, rb = b >> 4, rl = b & 15;
        const fv4* xp4 = (const fv4*)(x + (size_t)b * K_IN);
        fv4 xv[4];
#pragma unroll
        for (int j = 0; j < 4; ++j) xv[j] = xp4[t + j * 256];
        float acc[16];
#pragma unroll
        for (int r = 0; r < 16; ++r) {
            const fv4* ap = (const fv4*)(la + (size_t)r * K_IN);
            float s = 0.f;
#pragma unroll
            for (int j = 0; j < 4; ++j) {
                fv4 av = ap[t + j * 256];
                s = fmaf(xv[j].x, av.x, s);
                s = fmaf(xv[j].y, av.y, s);
                s = fmaf(xv[j].z, av.z, s);
                s = fmaf(xv[j].w, av.w, s);
            }
            acc[r] = s;
        }
#pragma unroll
        for (int r = 0; r < 16; ++r) {
#pragma unroll
            for (int off = 1; off < 64; off <<= 1)
                acc[r] += __shfl_xor(acc[r], off);
        }
        int lane = t & 63, w = t >> 6;
        if (lane < 16) red[w][lane] = acc[lane];
        __syncthreads();
        if (t < 8) {
            int gl = t;
            union { p2 h[4]; iv4 v; } u;
            u.v = iv4{0, 0, 0, 0};
            if (gl < 2) {
#pragma unroll
                for (int e2 = 0; e2 < 4; ++e2) {
                    int k0 = gl * 8 + e2 * 2;
                    float v0 = red[0][k0] + red[1][k0] + red[2][k0] + red[3][k0];
                    float v1 = red[0][k0+1] + red[1][k0+1] + red[2][k0+1] + red[3][k0+1];
                    u.h[e2] = __builtin_amdgcn_cvt_pkrtz(v0, v1);
                }
            }
            *(iv4*)(xp + (((size_t)rb * NG + 512 + gl) * 16 + rl) * 8) = u.v;
        }
    } else if (bid < 2048) {
        int idx = bid - 1024;
        int cb = idx >> 2, part = idx & 3;
        int c0 = part * 2;
        int o_l = t >> 4, gi_l = t & 15;
#pragma unroll 1
        for (int chunk = c0; chunk < c0 + 2; ++chunk) {
#pragma unroll
            for (int i = 0; i < 2; ++i) {
                int gi = chunk * 32 + i * 16 + gi_l;
                int o = cb * 16 + o_l;
                const int* qp = qw + ((size_t)o * 256 + gi) * 8;
                iv4 q0 = *(const iv4*)qp;
                iv4 q1 = *(const iv4*)(qp + 4);
                float s = sc[(size_t)o * 256 + gi];
                _Float16 c0h = (_Float16)(s * (2.0f / 15.0f));
                _Float16 c1h = (_Float16)(-s);
                h2 c0v = {c0h, c0h}, c1v = {c1h, c1h};
                h2 m1024 = {(_Float16)-1024.f, (_Float16)-1024.f};
                union { h2 h[4]; iv4 v; } w0, w1;
                int vals[8] = {q0.x, q0.y, q0.z, q0.w, q1.x, q1.y, q1.z, q1.w};
#pragma unroll
                for (int e = 0; e < 8; ++e) {
                    unsigned wv = (unsigned)vals[e];
                    unsigned qb = (wv & 15u) | ((wv & 0xF0u) << 12) | 0x64006400u;
                    h2 qh;
                    __builtin_memcpy(&qh, &qb, 4);
                    h2 r = (qh + m1024) * c0v + c1v;
                    if (e < 4) w0.h[e] = r; else w1.h[e - 4] = r;
                }
                int gl0 = i * 32 + 2 * gi_l;
                int s0 = o_l ^ gi_l;
                *(iv4*)(lsm + (gl0 * 16 + s0) * 16) = w0.v;
                *(iv4*)(lsm + ((gl0 + 1) * 16 + s0) * 16) = w1.v;
            }
            __syncthreads();
#pragma unroll
            for (int i = 0; i < 4; ++i) {
                int s_ = t + i * 256;
                int gl = s_ >> 4, oo = s_ & 15;
                iv4 v = *(const iv4*)(lsm + (gl * 16 + (oo ^ ((gl >> 1) & 15))) * 16);
                *(iv4*)(Wp + (((size_t)cb * NG + chunk * 64) * 16 + s_) * 8) = v;
            }
            __syncthreads();
        }
        if (part == 0 && t < 128) {
            int gl = t >> 4, rl = t & 15;
            int o = cb * 16 + rl;
            union { p2 h[4]; iv4 v; } u;
            u.v = iv4{0, 0, 0, 0};
            if (gl < 2) {
                float al = alphap[0];
                const float* wp = lb + (size_t)o * 16 + gl * 8;
#pragma unroll
                for (int e = 0; e < 4; ++e)
                    u.h[e] = __builtin_amdgcn_cvt_pkrtz(al * wp[2 * e], al * wp[2 * e + 1]);
            }
            *(iv4*)(Wp + (((size_t)cb * NG + 512 + gl) * 16 + rl) * 8) = u.v;
        }
    } else {
        int q2 = bid - 2048;
        int rb = q2 >> 2, kq = q2 & 3;
        int row = t >> 4, q = t & 15;
#pragma unroll 1
        for (int chunk = 0; chunk < 2; ++chunk) {
            int base_k = kq * 1024 + chunk * 512;
#pragma unroll
            for (int i = 0; i < 8; ++i) {
                int quad = q + i * 16;
                const float* p = x + (size_t)(rb * 16 + row) * K_IN + base_k + quad * 4;
                fv4 v = *(const fv4*)p;
                union { p2 h[2]; iv2 vv; } u;
                u.h[0] = __builtin_amdgcn_cvt_pkrtz(v.x, v.y);
                u.h[1] = __builtin_amdgcn_cvt_pkrtz(v.z, v.w);
                int gl = quad >> 1, sub = quad & 1;
                *(iv2*)(lsm + (gl * 16 + (row ^ (gl & 15))) * 16 + sub * 8) = u.vv;
            }
            __syncthreads();
#pragma unroll
            for (int i = 0; i < 4; ++i) {
                int s_ = t + i * 256;
                int gl = s_ >> 4, rr = s_ & 15;
                iv4 v = *(const iv4*)(lsm + (gl * 16 + (rr ^ (gl & 15))) * 16);
                *(iv4*)(xp + (((size_t)rb * NG + kq * 128 + chunk * 64) * 16 + s_) * 8) = v;
            }
            __syncthreads();
        }
    }
}

// ---------------------------------------------------------------------------
// GEMM (R11 structure, ASM-pinned pipeline): out = X @ W^T, f32 accum.
// 256 blocks x 512 thr (8 waves: wm,wn,kg=2x2x2; wave 64x64 over its k32
// half; 65 BK=64 steps). No LDS/barriers in main loop. Fragments loaded by
// asm volatile global_load_dwordx4 ("=v" outputs hold the register double
// buffer -- compiler cannot sink/collapse them; R13-R15 lesson). Counted
// s_waitcnt vmcnt(8) between tiles + sched_barrier(0) (rule #18). Running
// pointers advance 2048B per tile. LDS (64KB) only for the kg-split epilogue.
// ---------------------------------------------------------------------------
__global__ __launch_bounds__(512, 1) void qlora_gemm2(
        const _Float16* __restrict__ xp, const _Float16* __restrict__ Wp,
        float* __restrict__ out)
{
    __shared__ __align__(16) char lds[65536];

    int bid = blockIdx.x;
    int xcd = bid & 7, j = bid >> 3;    // j 0..31
    int by = j & 7, bx = xcd * 4 + (j >> 3);
    int bm0 = by << 7, bn0 = bx << 7;

    int t = threadIdx.x;
    int lane = t & 63;
    int wid = t >> 6;                   // 0..7
    int kg = wid & 1, wn = (wid >> 1) & 1, wm = wid >> 2;
    int rl = lane & 15, hq = lane >> 4;

    const char* pa[4];
    const char* pb[4];
#pragma unroll
    for (int m = 0; m < 4; ++m) {
        int rb = by * 8 + wm * 4 + m;
        pa[m] = (const char*)xp + (((size_t)rb * NG + kg * 4 + hq) * 16 + rl) * 16;
    }
#pragma unroll
    for (int n = 0; n < 4; ++n) {
        int cb = bx * 8 + wn * 4 + n;
        pb[n] = (const char*)Wp + (((size_t)cb * NG + kg * 4 + hq) * 16 + rl) * 16;
    }

    struct Frag { iv4 a[4]; iv4 b[4]; };
    Frag fA, fB;

    // asm loads: outputs pinned in VGPRs; pointers advance one tile (2048B).
    auto LOADASM = [&](Frag& f) {
#pragma unroll
        for (int m = 0; m < 4; ++m) {
            asm volatile("global_load_dwordx4 %0, %1, off"
                         : "=v"(f.a[m]) : "v"(pa[m]));
            pa[m] += 2048;
        }
#pragma unroll
        for (int n = 0; n < 4; ++n) {
            asm volatile("global_load_dwordx4 %0, %1, off"
                         : "=v"(f.b[n]) : "v"(pb[n]));
            pb[n] += 2048;
        }
    };

#define WAITP(N) do { \
        asm volatile("s_waitcnt vmcnt(" #N ")" ::: "memory"); \
        __builtin_amdgcn_sched_barrier(0); \
    } while (0)

    fv4 acc[4][4];
#pragma unroll
    for (int m = 0; m < 4; ++m)
#pragma unroll
        for (int n = 0; n < 4; ++n)
            acc[m][n] = fv4{0.f, 0.f, 0.f, 0.f};

    auto MFMAF = [&](const Frag& f) {
        union { iv4 v; f16x8 h; } ua[4], ub[4];
#pragma unroll
        for (int m = 0; m < 4; ++m) ua[m].v = f.a[m];
#pragma unroll
        for (int n = 0; n < 4; ++n) ub[n].v = f.b[n];
        __builtin_amdgcn_s_setprio(1);
#pragma unroll
        for (int m = 0; m < 4; ++m)
#pragma unroll
            for (int n = 0; n < 4; ++n)
                acc[m][n] = __builtin_amdgcn_mfma_f32_16x16x32_f16(
                    ua[m].h, ub[n].h, acc[m][n], 0, 0, 0);
        __builtin_amdgcn_s_setprio(0);
    };

    // ---- main loop: 65 tiles, dist-1 register double-buffer ----
    LOADASM(fA);                          // tile 0
#pragma unroll 1
    for (int ts = 0; ts < 64; ts += 2) {
        LOADASM(fB);                      // tile ts+1
        WAITP(8);                         // tile ts landed (fB's 8 in flight)
        MFMAF(fA);
        LOADASM(fA);                      // tile ts+2
        WAITP(8);                         // tile ts+1 landed
        MFMAF(fB);
    }
    WAITP(0);                             // tile 64 landed
    MFMAF(fA);

    // ---- kg-split reduction + store ----
    __syncthreads();
    if (kg == 1) {
        char* dmp = lds + (wm * 2 + wn) * 16384;
#pragma unroll
        for (int m = 0; m < 4; ++m)
#pragma unroll
            for (int n = 0; n < 4; ++n)
                *(fv4*)(dmp + (m * 4 + n) * 1024 + lane * 16) = acc[m][n];
    }
    __syncthreads();
    if (kg == 0) {
        const char* dmp = lds + (wm * 2 + wn) * 16384;
#pragma unroll
        for (int m = 0; m < 4; ++m) {
            int row0 = bm0 + wm * 64 + m * 16 + hq * 4;
#pragma unroll
            for (int n = 0; n < 4; ++n) {
                fv4 p = *(const fv4*)(dmp + (m * 4 + n) * 1024 + lane * 16);
                fv4 v = acc[m][n];
                v.x += p.x; v.y += p.y; v.z += p.z; v.w += p.w;
                int col = bn0 + wn * 64 + n * 16 + rl;
#pragma unroll
                for (int r = 0; r < 4; ++r)
                    out[(size_t)(row0 + r) * N_OUT + col] = v[r];
            }
        }
    }
#undef WAITP
}

extern "C" void kernel_launch(void* const* d_in, const int* in_sizes, int n_in,
                              void* d_out, int out_size, void* d_ws, size_t ws_size,
                              hipStream_t stream) {
    const float* x  = (const float*)d_in[0];
    const int*   qw = (const int*)d_in[1];
    const float* sc = (const float*)d_in[2];
    const float* la = (const float*)d_in[3];
    const float* lb = (const float*)d_in[4];
    const float* al = (const float*)d_in[5];
    float* out = (float*)d_out;

    const size_t WP_BYTES = (size_t)256 * NG * 16 * 16;   // 34,078,720
    _Float16* Wp = (_Float16*)d_ws;
    _Float16* xp = (_Float16*)((char*)d_ws + WP_BYTES);
    (void)ws_size; (void)n_in; (void)in_sizes; (void)out_size;

    prep_one<<<2304, 256, 0, stream>>>(x, la, qw, sc, lb, al, Wp, xp);
    qlora_gemm2<<<256, 512, 0, stream>>>(xp, Wp, out);
}